// Round 8
// baseline (1877.929 us; speedup 1.0000x reference)
//
#include <hip/hip_runtime.h>
#include <hip/hip_fp16.h>

#define H_ 1024
#define B_ 256
#define T_ 256
#define C_ 10

typedef _Float16 f16x8 __attribute__((ext_vector_type(8)));
typedef float f32x4 __attribute__((ext_vector_type(4)));

__device__ __forceinline__ float sigm_f(float v) { return 1.f / (1.f + __expf(-v)); }
__device__ __forceinline__ float tanh_f(float v) {
  v = fminf(fmaxf(v, -15.f), 15.f);
  float e = __expf(2.f * v);
  return (e - 1.f) / (e + 1.f);
}

// cross-XCD-safe coherence-point load (bypasses L1+L2) — slow-path h reads
__device__ __forceinline__ f16x8 load_h8_agent(const _Float16* p) {
  const unsigned long long* q = reinterpret_cast<const unsigned long long*>(p);
  unsigned long long lo = __hip_atomic_load(q,     __ATOMIC_RELAXED, __HIP_MEMORY_SCOPE_AGENT);
  unsigned long long hi = __hip_atomic_load(q + 1, __ATOMIC_RELAXED, __HIP_MEMORY_SCOPE_AGENT);
  union { unsigned long long u[2]; f16x8 v; } r;
  r.u[0] = lo; r.u[1] = hi;
  return r.v;
}

// zero flags/scal/h0 with agent-scope stores (write-through to IC: no dirty
// L2 lines anywhere -> no eviction races with the poison fill or past replays)
__global__ void lstm_init(unsigned* __restrict__ flags, int flagDw,
                          unsigned* __restrict__ scal,
                          unsigned* __restrict__ h0u, int h0Dw) {
  int i = blockIdx.x * blockDim.x + threadIdx.x;
  int n = gridDim.x * blockDim.x;
  for (int k = i; k < flagDw; k += n)
    __hip_atomic_store(flags + k, 0u, __ATOMIC_RELAXED, __HIP_MEMORY_SCOPE_AGENT);
  for (int k = i; k < 1024; k += n)
    __hip_atomic_store(scal + k, 0u, __ATOMIC_RELAXED, __HIP_MEMORY_SCOPE_AGENT);
  for (int k = i; k < h0Dw; k += n)
    __hip_atomic_store(h0u + k, 0u, __ATOMIC_RELAXED, __HIP_MEMORY_SCOPE_AGENT);
}

// Persistent LSTM. 256 WGs = 32 row-groups (r) x 8 col-groups (g); each WG:
// 32 hidden units x 32 batch cols, all 4 gates; weights stationary in VGPRs
// (row permutation m = 4*u + gate). Col-groups are communication-CLOSED ->
// same-XCD L2 messaging when the runtime vote confirms co-location.
// R8: (1) nt-prefetch of each WG's own h(t+1) output lines right after the
// poll -> write-allocate HBM fills overlap MFMA instead of stalling the
// drain; (2) per-wave fire-and-forget sc1 fetch_add flag publish (target 8
// arrivals) -> removes barrier+publish round-trip from the critical path.
// Flags are ALWAYS sc1/agent (replay-safe: never L2-cached). h fast-path is
// plain stores/loads on a 257-buffer fresh-address rotation (R7-proven).
__global__ __launch_bounds__(512, 2) void lstm_main(
    const float* __restrict__ x,
    const float* __restrict__ Wgh, const float* __restrict__ Wih,
    const float* __restrict__ Wfh, const float* __restrict__ Woh,
    const float* __restrict__ Wgx, const float* __restrict__ Wix,
    const float* __restrict__ Wfx, const float* __restrict__ Wox,
    const float* __restrict__ bg, const float* __restrict__ bi,
    const float* __restrict__ bf, const float* __restrict__ bo,
    _Float16* __restrict__ hT, unsigned int* __restrict__ flags,
    unsigned int* __restrict__ scal, int rot)
{
  const int bid  = blockIdx.x;
  const int g    = bid & 7;      // col group (one XCD, verified by vote)
  const int r    = bid >> 3;     // row group 0..31
  const int tid  = threadIdx.x;
  const int wid  = tid >> 6;     // wave 0..7
  const int lane = tid & 63;
  const int mg   = wid >> 2;     // M-group 0..1
  const int kg   = wid & 3;      // K-slice 0..3
  const int q    = lane >> 4;    // 0..3
  const int rlo  = lane & 15;
  const int c0   = g * 32;       // batch col base
  const size_t HB = (size_t)B_ * H_;

  __shared__ float part[32 * 4 * 128];  // [c_local][kg][m] f32, XOR-swizzled
  __shared__ unsigned mode_sh;

  // ---- per-col-group XCD co-location vote (machinery proven r3-r7) --------
  {
    unsigned xcc;
    asm volatile("s_getreg_b32 %0, hwreg(HW_REG_XCC_ID)" : "=s"(xcc));
    if (tid == 0) {
      unsigned* mask  = scal + g;
      unsigned* ready = scal + 8 + g;
      __hip_atomic_fetch_or(mask, 1u << (xcc & 31),
                            __ATOMIC_RELAXED, __HIP_MEMORY_SCOPE_AGENT);
      __hip_atomic_fetch_add(ready, 1u, __ATOMIC_RELEASE, __HIP_MEMORY_SCOPE_AGENT);
      int gd = 0; bool trip = false;
      while (__hip_atomic_load(ready, __ATOMIC_RELAXED, __HIP_MEMORY_SCOPE_AGENT) < 32u) {
        if (++gd > (1 << 22)) { trip = true; break; }
        __builtin_amdgcn_s_sleep(8);
      }
      unsigned m = __hip_atomic_load(mask, __ATOMIC_ACQUIRE, __HIP_MEMORY_SCOPE_AGENT);
      mode_sh = (rot && !trip && __popc((int)m) == 1) ? 1u : 2u;
    }
    __syncthreads();
  }
  const bool fast = (mode_sh == 1u);

  // ---- A fragments: stationary weights in registers -----------------------
  f16x8 A[32];
  {
    const int gate = rlo & 3;
    const float* Wsel = (gate == 0) ? Wgh : (gate == 1) ? Wih : (gate == 2) ? Wfh : Woh;
    #pragma unroll
    for (int f = 0; f < 32; ++f) {
      const int mt  = f >> 3, kkl = f & 7;
      const int u   = mg * 16 + mt * 4 + (rlo >> 2);
      const int k   = kg * 256 + kkl * 32 + q * 8;
      const float4* p = reinterpret_cast<const float4*>(
          Wsel + (size_t)(r * 32 + u) * H_ + k);
      float4 lo = p[0], hi = p[1];
      f16x8 a;
      a[0]=(_Float16)lo.x; a[1]=(_Float16)lo.y; a[2]=(_Float16)lo.z; a[3]=(_Float16)lo.w;
      a[4]=(_Float16)hi.x; a[5]=(_Float16)hi.y; a[6]=(_Float16)hi.z; a[7]=(_Float16)hi.w;
      A[f] = a;
    }
  }

  // ---- per-thread elementwise constants -----------------------------------
  const int c_l = tid >> 4;
  const int uu  = tid & 15;
  float wx0[4], wx1[4], bb0[4], bb1[4];
  {
    const int u0 = r * 32 + uu, u1 = u0 + 16;
    wx0[0]=Wgx[u0]; wx0[1]=Wix[u0]; wx0[2]=Wfx[u0]; wx0[3]=Wox[u0];
    wx1[0]=Wgx[u1]; wx1[1]=Wix[u1]; wx1[2]=Wfx[u1]; wx1[3]=Wox[u1];
    bb0[0]=bg[u0];  bb0[1]=bi[u0];  bb0[2]=bf[u0];  bb0[3]=bo[u0];
    bb1[0]=bg[u1];  bb1[1]=bi[u1];  bb1[2]=bf[u1];  bb1[3]=bo[u1];
  }
  float cs0 = 0.f, cs1 = 0.f;
  const float* xrow = x + (size_t)(c0 + c_l) * T_;

  const int flagIdxPoll = (g * 32 + kg * 8 + (lane & 7)) * 16;
  const int flagIdxOwn  = (g * 32 + r) * 16;

  for (int t = 0; t < T_; ++t) {
    // ---- rotated (fresh-address) or r6 (parity) buffers -------------------
    const _Float16* hbr = hT + (size_t)(rot ? t : (t & 1)) * HB;
    _Float16*       hbw = hT + (size_t)(rot ? (t + 1) : ((t + 1) & 1)) * HB;
    unsigned* pub = (rot ? flags + (size_t)t * 4096 : flags) + flagIdxOwn;

    // ---- per-wave wait: 8 producers x 8 wave-arrivals each ----
    if (t > 0) {
      unsigned* myf = (rot ? flags + (size_t)(t - 1) * 4096 : flags) + flagIdxPoll;
      const unsigned tgt = rot ? 8u : 8u * (unsigned)t;
      int guard = 0;
      for (;;) {
        unsigned v = tgt;
        if (lane < 8)
          v = __hip_atomic_load(myf, __ATOMIC_RELAXED, __HIP_MEMORY_SCOPE_AGENT);
        if (__all((int)(v >= tgt))) break;
        if (++guard > (1 << 20)) break;  // bailout: fails absmax, never hangs
        __builtin_amdgcn_s_sleep(1);
      }
      asm volatile("" ::: "memory");
    }

    // ---- nt-prefetch this WG's own h(t+1) output lines (write-allocate
    // fills overlap the GEMM; nt -> no L1 allocate -> no staleness risk).
    // Result kept live in pfv; consumed AFTER the drain (no mid-loop wait).
    unsigned pfv = 0;
    if (wid == 0 && lane < 32) {
      const unsigned* pf = reinterpret_cast<const unsigned*>(
          hbw + (size_t)(c0 + lane) * H_ + r * 32);
      asm volatile("global_load_dword %0, %1, off nt" : "=v"(pfv) : "v"(pf));
    }

    // ---- B-fragment loads: L2-cached (fast) or IC (slow) ----
    const _Float16* hb0 = hbr + (size_t)(c0 + rlo) * H_ + kg * 256 + q * 8;
    const _Float16* hb1 = hb0 + 16 * (size_t)H_;

    f16x8 B0[8], B1[8];
    if (fast) {
      #pragma unroll
      for (int kkl = 0; kkl < 8; ++kkl) {
        B0[kkl] = *reinterpret_cast<const f16x8*>(hb0 + kkl * 32);
        B1[kkl] = *reinterpret_cast<const f16x8*>(hb1 + kkl * 32);
      }
    } else {
      #pragma unroll
      for (int kkl = 0; kkl < 8; ++kkl) {
        B0[kkl] = load_h8_agent(hb0 + kkl * 32);
        B1[kkl] = load_h8_agent(hb1 + kkl * 32);
      }
    }

    // ---- GEMM: preactivations for this WG's 128(M) x 32(N) tile ----
    f32x4 acc[4][2];
    #pragma unroll
    for (int mt = 0; mt < 4; ++mt) {
      acc[mt][0] = (f32x4){0.f, 0.f, 0.f, 0.f};
      acc[mt][1] = (f32x4){0.f, 0.f, 0.f, 0.f};
    }
    #pragma unroll
    for (int kkl = 0; kkl < 8; ++kkl) {
      #pragma unroll
      for (int mt = 0; mt < 4; ++mt) {
        acc[mt][0] = __builtin_amdgcn_mfma_f32_16x16x32_f16(A[mt*8+kkl], B0[kkl], acc[mt][0], 0, 0, 0);
        acc[mt][1] = __builtin_amdgcn_mfma_f32_16x16x32_f16(A[mt*8+kkl], B1[kkl], acc[mt][1], 0, 0, 0);
      }
    }

    // ---- K-partials to LDS (C/D layout: col=lane&15, row=(lane>>4)*4+reg) ----
    #pragma unroll
    for (int mt = 0; mt < 4; ++mt) {
      #pragma unroll
      for (int nt = 0; nt < 2; ++nt) {
        const int c_loc = nt * 16 + rlo;
        const int m = mg * 64 + mt * 16 + 4 * q;
        unsigned addr = (unsigned)(c_loc * 2048 + kg * 512 + m * 4);
        addr ^= (unsigned)((c_loc & 7) << 4);
        *reinterpret_cast<f32x4*>(reinterpret_cast<char*>(part) + addr) = acc[mt][nt];
      }
    }
    __syncthreads();

    // ---- reduce over kg + gate nonlinearities + state update ----
    const float xv = xrow[t];
    unsigned short hbits0, hbits1;
    {
      unsigned lin = (unsigned)(c_l * 2048 + uu * 16);
      f32x4 s = *reinterpret_cast<const f32x4*>(
          reinterpret_cast<const char*>(part) + (lin ^ ((unsigned)(c_l & 7) << 4)));
      #pragma unroll
      for (int kgi = 1; kgi < 4; ++kgi) {
        unsigned l2 = lin + (unsigned)(kgi * 512);
        s += *reinterpret_cast<const f32x4*>(
            reinterpret_cast<const char*>(part) + (l2 ^ ((unsigned)(c_l & 7) << 4)));
      }
      float pg = s[0] + wx0[0]*xv + bb0[0];
      float pi = s[1] + wx0[1]*xv + bb0[1];
      float pf = s[2] + wx0[2]*xv + bb0[2];
      float po = s[3] + wx0[3]*xv + bb0[3];
      float gg = tanh_f(pg), ii = sigm_f(pi), ff = sigm_f(pf), oo = sigm_f(po);
      cs0 = gg * ii + cs0 * ff;
      hbits0 = __builtin_bit_cast(unsigned short, (_Float16)(tanh_f(cs0) * oo));
    }
    {
      unsigned lin = (unsigned)(c_l * 2048 + (uu + 16) * 16);
      f32x4 s = *reinterpret_cast<const f32x4*>(
          reinterpret_cast<const char*>(part) + (lin ^ ((unsigned)(c_l & 7) << 4)));
      #pragma unroll
      for (int kgi = 1; kgi < 4; ++kgi) {
        unsigned l2 = lin + (unsigned)(kgi * 512);
        s += *reinterpret_cast<const f32x4*>(
            reinterpret_cast<const char*>(part) + (l2 ^ ((unsigned)(c_l & 7) << 4)));
      }
      float pg = s[0] + wx1[0]*xv + bb1[0];
      float pi = s[1] + wx1[1]*xv + bb1[1];
      float pf = s[2] + wx1[2]*xv + bb1[2];
      float po = s[3] + wx1[3]*xv + bb1[3];
      float gg = tanh_f(pg), ii = sigm_f(pi), ff = sigm_f(pf), oo = sigm_f(po);
      cs1 = gg * ii + cs1 * ff;
      hbits1 = __builtin_bit_cast(unsigned short, (_Float16)(tanh_f(cs1) * oo));
    }

    // ---- store h(t+1) ----
    {
      _Float16* hout = hbw + (size_t)(c0 + c_l) * H_ + r * 32;
      int nb0 = __shfl_down((int)hbits0, 1);
      int nb1 = __shfl_down((int)hbits1, 1);
      if ((uu & 1) == 0) {
        unsigned v0 = (unsigned)hbits0 | ((unsigned)(unsigned short)nb0 << 16);
        unsigned v1 = (unsigned)hbits1 | ((unsigned)(unsigned short)nb1 << 16);
        unsigned int* p0 = reinterpret_cast<unsigned int*>(hout + uu);
        unsigned int* p1 = reinterpret_cast<unsigned int*>(hout + uu + 16);
        if (fast && t != T_ - 1) {
          // write-through -> shared XCD L2 (lines prefetched -> fast ack)
          *(volatile unsigned int*)p0 = v0;
          *(volatile unsigned int*)p1 = v1;
        } else {
          // slow mode + final step both modes (lstm_proj reads from IC)
          __hip_atomic_store(p0, v0, __ATOMIC_RELAXED, __HIP_MEMORY_SCOPE_AGENT);
          __hip_atomic_store(p1, v1, __ATOMIC_RELAXED, __HIP_MEMORY_SCOPE_AGENT);
        }
      }
    }
    // per-wave drain: this wave's h stores are acked (L2 fast / IC slow) ...
    asm volatile("s_waitcnt vmcnt(0)" ::: "memory");
    asm volatile("" :: "v"(pfv));   // retire prefetch sink (already drained)
    // ... then fire-and-forget publish: +1 wave-arrival (no result -> no wait)
    if (lane == 0)
      __hip_atomic_fetch_add(pub, 1u, __ATOMIC_RELAXED, __HIP_MEMORY_SCOPE_AGENT);
    __syncthreads();   // LDS reuse safety for the next step
  }
}

// out[b][cls] = sum_u W_ph[cls][u] * h_final[u][b] + b_p[cls]
__global__ void lstm_proj(const _Float16* __restrict__ hfin,
                          const float* __restrict__ Wph,
                          const float* __restrict__ bp,
                          float* __restrict__ out)
{
  const int b = blockIdx.x;
  const int l = threadIdx.x;
  const _Float16* hrow = hfin + (size_t)b * H_;
  float p[C_];
  #pragma unroll
  for (int cls = 0; cls < C_; ++cls) p[cls] = 0.f;
  for (int u = l; u < H_; u += 64) {
    float hv = (float)hrow[u];
    #pragma unroll
    for (int cls = 0; cls < C_; ++cls) p[cls] += hv * Wph[cls * H_ + u];
  }
  #pragma unroll
  for (int cls = 0; cls < C_; ++cls) {
    float v = p[cls];
    #pragma unroll
    for (int off = 32; off > 0; off >>= 1) v += __shfl_down(v, off);
    if (l == 0) out[b * C_ + cls] = v + bp[cls];
  }
}

extern "C" void kernel_launch(void* const* d_in, const int* in_sizes, int n_in,
                              void* d_out, int out_size, void* d_ws, size_t ws_size,
                              hipStream_t stream) {
  const float* x   = (const float*)d_in[0];
  const float* Wgx = (const float*)d_in[1];
  const float* Wgh = (const float*)d_in[2];
  const float* Wix = (const float*)d_in[3];
  const float* Wih = (const float*)d_in[4];
  const float* Wfx = (const float*)d_in[5];
  const float* Wfh = (const float*)d_in[6];
  const float* Wox = (const float*)d_in[7];
  const float* Woh = (const float*)d_in[8];
  const float* Wph = (const float*)d_in[9];
  const float* bg  = (const float*)d_in[10];
  const float* bi  = (const float*)d_in[11];
  const float* bf  = (const float*)d_in[12];
  const float* bo  = (const float*)d_in[13];
  const float* bp  = (const float*)d_in[14];
  float* out = (float*)d_out;

  const size_t HB = (size_t)B_ * H_;                     // elems per h buffer
  // rot layout: [0,4MB) flag rotation (T x 16KB); [4MB,+4KB) vote scalars;
  // [8MB, 8MB+257*512KB) h rotation (fresh addresses every step).
  const size_t need = (8u << 20) + (size_t)(T_ + 1) * HB * sizeof(_Float16);
  const int rot = (ws_size >= need) ? 1 : 0;

  unsigned *flags, *scal; _Float16 *hT; int flagDw;
  if (rot) {
    flags  = (unsigned*)d_ws;                            // 4 MB
    scal   = (unsigned*)((char*)d_ws + (4u << 20));      // 4 KB
    hT     = (_Float16*)((char*)d_ws + (8u << 20));      // 257 buffers
    flagDw = T_ * 4096;
  } else {
    hT     = (_Float16*)d_ws;                            // 2 buffers (1 MB)
    flags  = (unsigned*)((char*)d_ws + 2 * HB * sizeof(_Float16));
    scal   = flags + 4096;
    flagDw = 4096;
  }

  lstm_init<<<256, 256, 0, stream>>>(flags, flagDw, scal,
                                     (unsigned*)hT, (int)(HB / 2));
  lstm_main<<<256, 512, 0, stream>>>(x, Wgh, Wih, Wfh, Woh,
                                     Wgx, Wix, Wfx, Wox,
                                     bg, bi, bf, bo, hT, flags, scal, rot);
  lstm_proj<<<256, 64, 0, stream>>>(hT + (size_t)(rot ? T_ : 0) * HB,
                                    Wph, bp, out);
}

// Round 9
// 1793.043 us; speedup vs baseline: 1.0473x; 1.0473x over previous
//
#include <hip/hip_runtime.h>
#include <hip/hip_fp16.h>

#define H_ 1024
#define B_ 256
#define T_ 256
#define C_ 10

typedef _Float16 f16x8 __attribute__((ext_vector_type(8)));
typedef float f32x4 __attribute__((ext_vector_type(4)));

__device__ __forceinline__ float sigm_f(float v) { return 1.f / (1.f + __expf(-v)); }
__device__ __forceinline__ float tanh_f(float v) {
  v = fminf(fmaxf(v, -15.f), 15.f);
  float e = __expf(2.f * v);
  return (e - 1.f) / (e + 1.f);
}

// invalidate this CU's vector L1 AND wait for completion (R4's missing wait).
// After this, plain loads must come from (shared, co-located) L2.
__device__ __forceinline__ void inv_l1_wait() {
  asm volatile("buffer_inv sc0\n\ts_waitcnt vmcnt(0)" ::: "memory");
}

// cross-XCD-safe coherence-point load (bypasses L1+L2) — slow-path h reads
__device__ __forceinline__ f16x8 load_h8_agent(const _Float16* p) {
  const unsigned long long* q = reinterpret_cast<const unsigned long long*>(p);
  unsigned long long lo = __hip_atomic_load(q,     __ATOMIC_RELAXED, __HIP_MEMORY_SCOPE_AGENT);
  unsigned long long hi = __hip_atomic_load(q + 1, __ATOMIC_RELAXED, __HIP_MEMORY_SCOPE_AGENT);
  union { unsigned long long u[2]; f16x8 v; } r;
  r.u[0] = lo; r.u[1] = hi;
  return r.v;
}

// zero flags/scal/h0 with agent-scope stores (write-through to IC; every
// kernel launch starts with invalidated L1/L2 -> all WGs read these zeros)
__global__ void lstm_init(unsigned* __restrict__ flags, int flagDw,
                          unsigned* __restrict__ scal,
                          unsigned* __restrict__ h0u, int h0Dw) {
  int i = blockIdx.x * blockDim.x + threadIdx.x;
  int n = gridDim.x * blockDim.x;
  for (int k = i; k < flagDw; k += n)
    __hip_atomic_store(flags + k, 0u, __ATOMIC_RELAXED, __HIP_MEMORY_SCOPE_AGENT);
  for (int k = i; k < 1024; k += n)
    __hip_atomic_store(scal + k, 0u, __ATOMIC_RELAXED, __HIP_MEMORY_SCOPE_AGENT);
  for (int k = i; k < h0Dw; k += n)
    __hip_atomic_store(h0u + k, 0u, __ATOMIC_RELAXED, __HIP_MEMORY_SCOPE_AGENT);
}

// Persistent LSTM. 256 WGs = 32 row-groups (r) x 8 col-groups (g); each WG:
// 32 hidden units x 32 batch cols, all 4 gates; weights stationary in VGPRs
// (row permutation m = 4*u + gate). Col-groups are communication-CLOSED and
// co-located on one XCD (runtime vote).
// FAST: h in 2 parity buffers, permanently L2-resident (no write-allocate HBM
//   fills after warmup). Producers: plain write-through stores -> shared L2.
//   Consumers: after the poll, buffer_inv sc0 + s_waitcnt (L1 invalidate,
//   completed), then plain loads served by the shared L2. Flags stay
//   sc1/agent (r6-proven visible -> no hang path ever).
// SLOW (vote failed): exact r6 agent-scope semantics.
// Both modes: identical FP ops in identical order -> identical bits.
__global__ __launch_bounds__(512, 2) void lstm_main(
    const float* __restrict__ x,
    const float* __restrict__ Wgh, const float* __restrict__ Wih,
    const float* __restrict__ Wfh, const float* __restrict__ Woh,
    const float* __restrict__ Wgx, const float* __restrict__ Wix,
    const float* __restrict__ Wfx, const float* __restrict__ Wox,
    const float* __restrict__ bg, const float* __restrict__ bi,
    const float* __restrict__ bf, const float* __restrict__ bo,
    _Float16* __restrict__ hT, unsigned int* __restrict__ flags,
    unsigned int* __restrict__ scal)
{
  const int bid  = blockIdx.x;
  const int g    = bid & 7;      // col group (one XCD, verified by vote)
  const int r    = bid >> 3;     // row group 0..31
  const int tid  = threadIdx.x;
  const int wid  = tid >> 6;     // wave 0..7
  const int lane = tid & 63;
  const int mg   = wid >> 2;     // M-group 0..1
  const int kg   = wid & 3;      // K-slice 0..3
  const int q    = lane >> 4;    // 0..3
  const int rlo  = lane & 15;
  const int c0   = g * 32;       // batch col base
  const size_t HB = (size_t)B_ * H_;

  __shared__ float part[32 * 4 * 128];  // [c_local][kg][m] f32, XOR-swizzled
  __shared__ unsigned mode_sh;

  // ---- per-col-group XCD co-location vote (machinery proven r3-r8) --------
  {
    unsigned xcc;
    asm volatile("s_getreg_b32 %0, hwreg(HW_REG_XCC_ID)" : "=s"(xcc));
    if (tid == 0) {
      unsigned* mask  = scal + g;
      unsigned* ready = scal + 8 + g;
      __hip_atomic_fetch_or(mask, 1u << (xcc & 31),
                            __ATOMIC_RELAXED, __HIP_MEMORY_SCOPE_AGENT);
      __hip_atomic_fetch_add(ready, 1u, __ATOMIC_RELEASE, __HIP_MEMORY_SCOPE_AGENT);
      int gd = 0; bool trip = false;
      while (__hip_atomic_load(ready, __ATOMIC_RELAXED, __HIP_MEMORY_SCOPE_AGENT) < 32u) {
        if (++gd > (1 << 22)) { trip = true; break; }
        __builtin_amdgcn_s_sleep(8);
      }
      unsigned m = __hip_atomic_load(mask, __ATOMIC_ACQUIRE, __HIP_MEMORY_SCOPE_AGENT);
      mode_sh = (!trip && __popc((int)m) == 1) ? 1u : 2u;
    }
    __syncthreads();
  }
  const bool fast = (mode_sh == 1u);

  // ---- A fragments: stationary weights in registers -----------------------
  f16x8 A[32];
  {
    const int gate = rlo & 3;
    const float* Wsel = (gate == 0) ? Wgh : (gate == 1) ? Wih : (gate == 2) ? Wfh : Woh;
    #pragma unroll
    for (int f = 0; f < 32; ++f) {
      const int mt  = f >> 3, kkl = f & 7;
      const int u   = mg * 16 + mt * 4 + (rlo >> 2);
      const int k   = kg * 256 + kkl * 32 + q * 8;
      const float4* p = reinterpret_cast<const float4*>(
          Wsel + (size_t)(r * 32 + u) * H_ + k);
      float4 lo = p[0], hi = p[1];
      f16x8 a;
      a[0]=(_Float16)lo.x; a[1]=(_Float16)lo.y; a[2]=(_Float16)lo.z; a[3]=(_Float16)lo.w;
      a[4]=(_Float16)hi.x; a[5]=(_Float16)hi.y; a[6]=(_Float16)hi.z; a[7]=(_Float16)hi.w;
      A[f] = a;
    }
  }

  // ---- per-thread elementwise constants -----------------------------------
  const int c_l = tid >> 4;
  const int uu  = tid & 15;
  float wx0[4], wx1[4], bb0[4], bb1[4];
  {
    const int u0 = r * 32 + uu, u1 = u0 + 16;
    wx0[0]=Wgx[u0]; wx0[1]=Wix[u0]; wx0[2]=Wfx[u0]; wx0[3]=Wox[u0];
    wx1[0]=Wgx[u1]; wx1[1]=Wix[u1]; wx1[2]=Wfx[u1]; wx1[3]=Wox[u1];
    bb0[0]=bg[u0];  bb0[1]=bi[u0];  bb0[2]=bf[u0];  bb0[3]=bo[u0];
    bb1[0]=bg[u1];  bb1[1]=bi[u1];  bb1[2]=bf[u1];  bb1[3]=bo[u1];
  }
  float cs0 = 0.f, cs1 = 0.f;
  const float* xrow = x + (size_t)(c0 + c_l) * T_;

  unsigned int* myflags = flags + ((size_t)(g * 32 + kg * 8 + (lane & 7)) * 16);
  unsigned int* ownflag = flags + ((size_t)(g * 32 + r) * 16);

  for (int t = 0; t < T_; ++t) {
    // ---- per-wave wait: only the 8 producers feeding this K-slice ----
    if (t > 0) {
      const unsigned tgt = (unsigned)t;
      int guard = 0;
      const int gmax = fast ? (1 << 18) : (1 << 20);
      for (;;) {
        unsigned v = tgt;
        if (lane < 8)
          v = __hip_atomic_load(myflags, __ATOMIC_RELAXED, __HIP_MEMORY_SCOPE_AGENT);
        if (__all((int)(v >= tgt))) break;
        if (++guard > gmax) break;  // bailout: fails absmax, never hangs
        __builtin_amdgcn_s_sleep(1);
      }
      asm volatile("" ::: "memory");
      // fast path: h lines for this parity buffer may be stale in OUR L1
      // (last read 2 steps ago). Invalidate L1 and WAIT, then read from the
      // shared XCD L2 where the producers' write-through stores live.
      if (fast) inv_l1_wait();
    }

    const _Float16* hbr = hT + (size_t)(t & 1) * HB;
    _Float16*       hbw = hT + (size_t)((t + 1) & 1) * HB;

    // ---- B-fragment loads: plain/L2 (fast) or agent/IC (slow) ----
    const _Float16* hb0 = hbr + (size_t)(c0 + rlo) * H_ + kg * 256 + q * 8;
    const _Float16* hb1 = hb0 + 16 * (size_t)H_;

    f16x8 B0[8], B1[8];
    if (fast) {
      #pragma unroll
      for (int kkl = 0; kkl < 8; ++kkl) {
        B0[kkl] = *reinterpret_cast<const f16x8*>(hb0 + kkl * 32);
        B1[kkl] = *reinterpret_cast<const f16x8*>(hb1 + kkl * 32);
      }
    } else {
      #pragma unroll
      for (int kkl = 0; kkl < 8; ++kkl) {
        B0[kkl] = load_h8_agent(hb0 + kkl * 32);
        B1[kkl] = load_h8_agent(hb1 + kkl * 32);
      }
    }

    // ---- GEMM: preactivations for this WG's 128(M) x 32(N) tile ----
    f32x4 acc[4][2];
    #pragma unroll
    for (int mt = 0; mt < 4; ++mt) {
      acc[mt][0] = (f32x4){0.f, 0.f, 0.f, 0.f};
      acc[mt][1] = (f32x4){0.f, 0.f, 0.f, 0.f};
    }
    #pragma unroll
    for (int kkl = 0; kkl < 8; ++kkl) {
      #pragma unroll
      for (int mt = 0; mt < 4; ++mt) {
        acc[mt][0] = __builtin_amdgcn_mfma_f32_16x16x32_f16(A[mt*8+kkl], B0[kkl], acc[mt][0], 0, 0, 0);
        acc[mt][1] = __builtin_amdgcn_mfma_f32_16x16x32_f16(A[mt*8+kkl], B1[kkl], acc[mt][1], 0, 0, 0);
      }
    }

    // ---- K-partials to LDS (C/D layout: col=lane&15, row=(lane>>4)*4+reg) ----
    #pragma unroll
    for (int mt = 0; mt < 4; ++mt) {
      #pragma unroll
      for (int nt = 0; nt < 2; ++nt) {
        const int c_loc = nt * 16 + rlo;
        const int m = mg * 64 + mt * 16 + 4 * q;
        unsigned addr = (unsigned)(c_loc * 2048 + kg * 512 + m * 4);
        addr ^= (unsigned)((c_loc & 7) << 4);
        *reinterpret_cast<f32x4*>(reinterpret_cast<char*>(part) + addr) = acc[mt][nt];
      }
    }
    __syncthreads();

    // ---- reduce over kg + gate nonlinearities + state update ----
    const float xv = xrow[t];
    unsigned short hbits0, hbits1;
    {
      unsigned lin = (unsigned)(c_l * 2048 + uu * 16);
      f32x4 s = *reinterpret_cast<const f32x4*>(
          reinterpret_cast<const char*>(part) + (lin ^ ((unsigned)(c_l & 7) << 4)));
      #pragma unroll
      for (int kgi = 1; kgi < 4; ++kgi) {
        unsigned l2 = lin + (unsigned)(kgi * 512);
        s += *reinterpret_cast<const f32x4*>(
            reinterpret_cast<const char*>(part) + (l2 ^ ((unsigned)(c_l & 7) << 4)));
      }
      float pg = s[0] + wx0[0]*xv + bb0[0];
      float pi = s[1] + wx0[1]*xv + bb0[1];
      float pf = s[2] + wx0[2]*xv + bb0[2];
      float po = s[3] + wx0[3]*xv + bb0[3];
      float gg = tanh_f(pg), ii = sigm_f(pi), ff = sigm_f(pf), oo = sigm_f(po);
      cs0 = gg * ii + cs0 * ff;
      hbits0 = __builtin_bit_cast(unsigned short, (_Float16)(tanh_f(cs0) * oo));
    }
    {
      unsigned lin = (unsigned)(c_l * 2048 + (uu + 16) * 16);
      f32x4 s = *reinterpret_cast<const f32x4*>(
          reinterpret_cast<const char*>(part) + (lin ^ ((unsigned)(c_l & 7) << 4)));
      #pragma unroll
      for (int kgi = 1; kgi < 4; ++kgi) {
        unsigned l2 = lin + (unsigned)(kgi * 512);
        s += *reinterpret_cast<const f32x4*>(
            reinterpret_cast<const char*>(part) + (l2 ^ ((unsigned)(c_l & 7) << 4)));
      }
      float pg = s[0] + wx1[0]*xv + bb1[0];
      float pi = s[1] + wx1[1]*xv + bb1[1];
      float pf = s[2] + wx1[2]*xv + bb1[2];
      float po = s[3] + wx1[3]*xv + bb1[3];
      float gg = tanh_f(pg), ii = sigm_f(pi), ff = sigm_f(pf), oo = sigm_f(po);
      cs1 = gg * ii + cs1 * ff;
      hbits1 = __builtin_bit_cast(unsigned short, (_Float16)(tanh_f(cs1) * oo));
    }

    // ---- store h(t+1) ----
    {
      _Float16* hout = hbw + (size_t)(c0 + c_l) * H_ + r * 32;
      int nb0 = __shfl_down((int)hbits0, 1);
      int nb1 = __shfl_down((int)hbits1, 1);
      if ((uu & 1) == 0) {
        unsigned v0 = (unsigned)hbits0 | ((unsigned)(unsigned short)nb0 << 16);
        unsigned v1 = (unsigned)hbits1 | ((unsigned)(unsigned short)nb1 << 16);
        unsigned int* p0 = reinterpret_cast<unsigned int*>(hout + uu);
        unsigned int* p1 = reinterpret_cast<unsigned int*>(hout + uu + 16);
        if (fast && t != T_ - 1) {
          // plain write-through -> shared XCD L2 (line L2-resident: no fill)
          *(volatile unsigned int*)p0 = v0;
          *(volatile unsigned int*)p1 = v1;
        } else {
          // slow mode + final step both modes (lstm_proj reads via IC)
          __hip_atomic_store(p0, v0, __ATOMIC_RELAXED, __HIP_MEMORY_SCOPE_AGENT);
          __hip_atomic_store(p1, v1, __ATOMIC_RELAXED, __HIP_MEMORY_SCOPE_AGENT);
        }
      }
    }
    // drain: h stores acked (L2 fast / IC slow) before the flag publishes
    asm volatile("s_waitcnt vmcnt(0)" ::: "memory");
    __syncthreads();
    if (tid == 0)
      __hip_atomic_store(ownflag, (unsigned)(t + 1),
                         __ATOMIC_RELAXED, __HIP_MEMORY_SCOPE_AGENT);
  }
}

// out[b][cls] = sum_u W_ph[cls][u] * h_final[u][b] + b_p[cls]
__global__ void lstm_proj(const _Float16* __restrict__ hfin,
                          const float* __restrict__ Wph,
                          const float* __restrict__ bp,
                          float* __restrict__ out)
{
  const int b = blockIdx.x;
  const int l = threadIdx.x;
  const _Float16* hrow = hfin + (size_t)b * H_;
  float p[C_];
  #pragma unroll
  for (int cls = 0; cls < C_; ++cls) p[cls] = 0.f;
  for (int u = l; u < H_; u += 64) {
    float hv = (float)hrow[u];
    #pragma unroll
    for (int cls = 0; cls < C_; ++cls) p[cls] += hv * Wph[cls * H_ + u];
  }
  #pragma unroll
  for (int cls = 0; cls < C_; ++cls) {
    float v = p[cls];
    #pragma unroll
    for (int off = 32; off > 0; off >>= 1) v += __shfl_down(v, off);
    if (l == 0) out[b * C_ + cls] = v + bp[cls];
  }
}

extern "C" void kernel_launch(void* const* d_in, const int* in_sizes, int n_in,
                              void* d_out, int out_size, void* d_ws, size_t ws_size,
                              hipStream_t stream) {
  const float* x   = (const float*)d_in[0];
  const float* Wgx = (const float*)d_in[1];
  const float* Wgh = (const float*)d_in[2];
  const float* Wix = (const float*)d_in[3];
  const float* Wih = (const float*)d_in[4];
  const float* Wfx = (const float*)d_in[5];
  const float* Wfh = (const float*)d_in[6];
  const float* Wox = (const float*)d_in[7];
  const float* Woh = (const float*)d_in[8];
  const float* Wph = (const float*)d_in[9];
  const float* bg  = (const float*)d_in[10];
  const float* bi  = (const float*)d_in[11];
  const float* bf  = (const float*)d_in[12];
  const float* bo  = (const float*)d_in[13];
  const float* bp  = (const float*)d_in[14];
  float* out = (float*)d_out;

  // ws layout: [0,1MB) hT fp16 parity buffers [2][B][H];
  //            [1MB,+16KB) per-producer flags (256 x 64B);
  //            [1MB+16KB,+4KB) vote scalars
  _Float16* hT = (_Float16*)d_ws;
  const size_t hT_bytes = (size_t)2 * B_ * H_ * sizeof(_Float16);  // 1 MiB
  unsigned int* flags = (unsigned int*)((char*)d_ws + hT_bytes);
  unsigned int* scal  = (unsigned int*)((char*)d_ws + hT_bytes + 16384);

  lstm_init<<<256, 256, 0, stream>>>(flags, 4096, scal,
                                     (unsigned*)hT, (int)(B_ * H_ / 2));
  lstm_main<<<256, 512, 0, stream>>>(x, Wgh, Wih, Wfh, Woh,
                                     Wgx, Wix, Wfx, Wox,
                                     bg, bi, bf, bo, hT, flags, scal);
  lstm_proj<<<256, 64, 0, stream>>>(hT, Wph, bp, out);
}